// Round 1
// baseline (2006.508 us; speedup 1.0000x reference)
//
#include <hip/hip_runtime.h>
#include <math.h>

// Problem constants (from reference): B=2, T=2048, C=1024, H=16, D=64.
#define BSZ 2
#define TSEQ 2048
#define CEMB 1024
#define NHEAD 16
#define HDIM 64

// ---------------------------------------------------------------------------
// Tiled fp32 GEMM + bias: C[M,N] = A[M,K] @ B[K,N] + bias[N]
// 64x64 tile, BK=16, 256 threads, each thread computes a 4x4 micro-tile.
// ---------------------------------------------------------------------------
#define GT 64
#define GBK 16

__global__ __launch_bounds__(256) void gemm_bias(
    const float* __restrict__ A, const float* __restrict__ B,
    const float* __restrict__ bias, float* __restrict__ C,
    int M, int N, int K)
{
    __shared__ float As[GBK][GT + 1];
    __shared__ float Bs[GBK][GT + 1];

    const int tid = threadIdx.x;
    const int tx = tid & 15;   // col group (4 cols each)
    const int ty = tid >> 4;   // row group (4 rows each)
    const int row0 = blockIdx.y * GT;
    const int col0 = blockIdx.x * GT;

    float acc[4][4] = {};

    for (int k0 = 0; k0 < K; k0 += GBK) {
        // A tile: GT rows x GBK cols -> As[k][m]; 16 consecutive lanes read
        // 16 consecutive floats of one A row.
        for (int i = tid; i < GT * GBK; i += 256) {
            int m = i >> 4;
            int kk = i & 15;
            As[kk][m] = A[(size_t)(row0 + m) * K + k0 + kk];
        }
        // B tile: GBK rows x GT cols -> Bs[k][n]; fully coalesced.
        for (int i = tid; i < GT * GBK; i += 256) {
            int kk = i >> 6;
            int n = i & 63;
            Bs[kk][n] = B[(size_t)(k0 + kk) * N + col0 + n];
        }
        __syncthreads();

        #pragma unroll
        for (int kk = 0; kk < GBK; ++kk) {
            float a[4], b[4];
            #pragma unroll
            for (int i = 0; i < 4; ++i) a[i] = As[kk][ty * 4 + i];
            #pragma unroll
            for (int j = 0; j < 4; ++j) b[j] = Bs[kk][tx * 4 + j];
            #pragma unroll
            for (int i = 0; i < 4; ++i)
                #pragma unroll
                for (int j = 0; j < 4; ++j)
                    acc[i][j] += a[i] * b[j];
        }
        __syncthreads();
    }

    #pragma unroll
    for (int i = 0; i < 4; ++i) {
        const int m = row0 + ty * 4 + i;
        #pragma unroll
        for (int j = 0; j < 4; ++j) {
            const int n = col0 + tx * 4 + j;
            C[(size_t)m * N + n] = acc[i][j] + bias[n];
        }
    }
}

// ---------------------------------------------------------------------------
// Flash-style causal attention (fp32).
// qkv: [B*T, 3C] with q at col h*64+d, k at C+h*64+d, v at 2C+h*64+d.
// out: [B*T, C] at col h*64+d  (== [b,t,h,d] flattened back to [b,t,c]).
// Grid: (B*H, T/64). Block: 256 threads = 64 rows x 4 groups.
// Thread (r,g) owns q-row r, d-slice [g*16, g*16+16) of the O accumulator,
// and computes scores for keys [g*16, g*16+16) of each 64-key tile.
// ---------------------------------------------------------------------------
__global__ __launch_bounds__(256) void flash_attn(
    const float* __restrict__ qkv, float* __restrict__ out)
{
    const int bh = blockIdx.x;
    const int b = bh / NHEAD, h = bh % NHEAD;
    const int qt = blockIdx.y;
    const int q0 = qt * 64;

    const size_t rs = 3 * CEMB;  // qkv row stride
    const float* qb = qkv + (size_t)b * TSEQ * rs + h * HDIM;
    const float* kb = qb + CEMB;
    const float* vb = qb + 2 * CEMB;

    __shared__ float Qs[64][HDIM + 1];
    __shared__ float Ks[64][HDIM + 1];
    __shared__ float Vs[64][HDIM + 1];
    __shared__ float Ps[64][64 + 1];
    __shared__ float redm[64][4];
    __shared__ float reds[64][4];
    __shared__ float mrow[64], lrow[64];

    const int tid = threadIdx.x;
    const int r = tid >> 2;
    const int g = tid & 3;

    // Load Q tile (coalesced groups of 64 floats).
    for (int i = tid; i < 64 * HDIM; i += 256) {
        int rr = i >> 6, dd = i & 63;
        Qs[rr][dd] = qb[(size_t)(q0 + rr) * rs + dd];
    }
    if (tid < 64) { mrow[tid] = -INFINITY; lrow[tid] = 0.f; }

    float O[16];
    #pragma unroll
    for (int j = 0; j < 16; ++j) O[j] = 0.f;

    const float scale = 0.03125f;  // 1/sqrt(C) = 1/32

    for (int kt = 0; kt <= qt; ++kt) {
        const int k0 = kt * 64;
        __syncthreads();  // protect Ks/Vs from previous iteration's readers
        for (int i = tid; i < 64 * HDIM; i += 256) {
            int rr = i >> 6, dd = i & 63;
            Ks[rr][dd] = kb[(size_t)(k0 + rr) * rs + dd];
            Vs[rr][dd] = vb[(size_t)(k0 + rr) * rs + dd];
        }
        __syncthreads();

        // Scores for row r, keys g*16..g*16+15.
        float s[16];
        float pm = -INFINITY;
        #pragma unroll
        for (int jj = 0; jj < 16; ++jj) {
            const int j = g * 16 + jj;
            float acc = 0.f;
            #pragma unroll
            for (int dd = 0; dd < HDIM; ++dd)
                acc += Qs[r][dd] * Ks[j][dd];
            acc *= scale;
            if (k0 + j > q0 + r) acc = -INFINITY;  // causal mask
            s[jj] = acc;
            pm = fmaxf(pm, acc);
        }
        redm[r][g] = pm;
        __syncthreads();

        const float mold = mrow[r];
        float mnew = fmaxf(fmaxf(redm[r][0], redm[r][1]),
                           fmaxf(redm[r][2], redm[r][3]));
        mnew = fmaxf(mold, mnew);

        float psum = 0.f;
        #pragma unroll
        for (int jj = 0; jj < 16; ++jj) {
            const float p = __expf(s[jj] - mnew);
            Ps[r][g * 16 + jj] = p;
            psum += p;
        }
        reds[r][g] = psum;

        const float sc = __expf(mold - mnew);  // first iter: exp(-inf)=0
        #pragma unroll
        for (int j = 0; j < 16; ++j) O[j] *= sc;
        __syncthreads();

        if (g == 0) {
            const float rowsum = reds[r][0] + reds[r][1] + reds[r][2] + reds[r][3];
            lrow[r] = lrow[r] * sc + rowsum;
            mrow[r] = mnew;
        }

        // O += P @ V  (this thread: d-slice g*16..g*16+15)
        #pragma unroll 8
        for (int k = 0; k < 64; ++k) {
            const float p = Ps[r][k];
            #pragma unroll
            for (int j = 0; j < 16; ++j)
                O[j] += p * Vs[k][g * 16 + j];
        }
    }

    __syncthreads();
    const float linv = 1.f / lrow[r];
    float* ob = out + (size_t)(b * TSEQ + q0 + r) * CEMB + h * HDIM + g * 16;
    #pragma unroll
    for (int j = 0; j < 16; ++j) ob[j] = O[j] * linv;
}

// ---------------------------------------------------------------------------
extern "C" void kernel_launch(void* const* d_in, const int* in_sizes, int n_in,
                              void* d_out, int out_size, void* d_ws, size_t ws_size,
                              hipStream_t stream)
{
    (void)in_sizes; (void)n_in; (void)out_size; (void)ws_size;

    const float* x      = (const float*)d_in[0];
    const float* w_qkv  = (const float*)d_in[1];
    const float* b_qkv  = (const float*)d_in[2];
    const float* w_proj = (const float*)d_in[3];
    const float* b_proj = (const float*)d_in[4];
    float* out = (float*)d_out;

    const int M = BSZ * TSEQ;        // 4096
    float* qkv = (float*)d_ws;                       // [M, 3C]  50.3 MB
    float* att = qkv + (size_t)M * 3 * CEMB;         // [M, C]   16.8 MB

    dim3 blk(256);
    // qkv = x @ w_qkv + b_qkv
    gemm_bias<<<dim3(3 * CEMB / GT, M / GT), blk, 0, stream>>>(
        x, w_qkv, b_qkv, qkv, M, 3 * CEMB, CEMB);
    // att = causal_softmax(q k^T / 32) v, heads recombined
    flash_attn<<<dim3(BSZ * NHEAD, TSEQ / 64), blk, 0, stream>>>(qkv, att);
    // out = att @ w_proj + b_proj
    gemm_bias<<<dim3(CEMB / GT, M / GT), blk, 0, stream>>>(
        att, w_proj, b_proj, out, M, CEMB, CEMB);
}

// Round 7
// 211.508 us; speedup vs baseline: 9.4867x; 9.4867x over previous
//
#include <hip/hip_runtime.h>
#include <math.h>

#define BSZ 2
#define TSEQ 2048
#define CEMB 1024
#define NHEAD 16
#define HDIM 64

typedef float f32x4 __attribute__((ext_vector_type(4)));
typedef short bf16x8 __attribute__((ext_vector_type(8)));

typedef __attribute__((address_space(3))) char lds_char;
typedef __attribute__((address_space(1))) const char gbl_char;

__device__ __forceinline__ void g2l16(const void* g, void* l) {
    // async global->LDS, 16B per lane; LDS dest = wave-uniform base + lane*16
    __builtin_amdgcn_global_load_lds((const gbl_char*)g, (lds_char*)l, 16, 0, 0);
}

__device__ __forceinline__ unsigned short f2bf(float x) {
    unsigned u = __float_as_uint(x);
    unsigned r = ((u >> 16) & 1u) + 0x7fffu;   // round-to-nearest-even
    return (unsigned short)((u + r) >> 16);
}

// ---------------------------------------------------------------------------
// fp32 -> bf16 elementwise (8 elems/thread, 16B stores)
// ---------------------------------------------------------------------------
__global__ __launch_bounds__(256) void conv_f32_bf16(
    const float* __restrict__ in, unsigned short* __restrict__ out)
{
    size_t i = ((size_t)blockIdx.x * 256 + threadIdx.x) * 8;
    float4 a = *(const float4*)(in + i);
    float4 b = *(const float4*)(in + i + 4);
    union { unsigned short u[8]; uint4 v; } pk;
    pk.u[0] = f2bf(a.x); pk.u[1] = f2bf(a.y); pk.u[2] = f2bf(a.z); pk.u[3] = f2bf(a.w);
    pk.u[4] = f2bf(b.x); pk.u[5] = f2bf(b.y); pk.u[6] = f2bf(b.z); pk.u[7] = f2bf(b.w);
    *(uint4*)(out + i) = pk.v;
}

// ---------------------------------------------------------------------------
// fp32 [K][N] -> bf16 transposed [N][K]
// ---------------------------------------------------------------------------
__global__ __launch_bounds__(256) void conv_transpose_bf16(
    const float* __restrict__ w, unsigned short* __restrict__ wT, int K, int N)
{
    __shared__ float t[32][33];
    const int n0 = blockIdx.x * 32, k0 = blockIdx.y * 32;
    const int tx = threadIdx.x & 31, ty = threadIdx.x >> 5;  // 32 x 8
    #pragma unroll
    for (int i = 0; i < 4; ++i)
        t[ty + i * 8][tx] = w[(size_t)(k0 + ty + i * 8) * N + n0 + tx];
    __syncthreads();
    #pragma unroll
    for (int i = 0; i < 4; ++i) {
        int r = ty + i * 8;
        wT[(size_t)(n0 + r) * K + k0 + tx] = f2bf(t[tx][r]);
    }
}

// ---------------------------------------------------------------------------
// bf16 MFMA GEMM: C[M,N] = A[M,K] @ BT[N,K]^T + bias
// 128x128 tile, BK=64, 256 threads (4 waves 2x2), 16x16x32 mfma.
// LDS tiles [128 rows][64 k] bf16 (128B rows), 16B-chunk XOR swizzle
// (chunk ^= row&7) applied to the GLOBAL source on stage + on ds_read.
// EPI=0: QKV epilogue (Q,K bf16 row-major; V transposed [b][h][d][t]).
// EPI=1: fp32 out + bias.
// ---------------------------------------------------------------------------
template <int EPI>
__global__ __launch_bounds__(256) void gemm_mfma(
    const unsigned short* __restrict__ A, const unsigned short* __restrict__ BT,
    const float* __restrict__ bias,
    unsigned short* __restrict__ qo, unsigned short* __restrict__ ko,
    unsigned short* __restrict__ vo, float* __restrict__ fo,
    int M, int N, int K)
{
    __shared__ __align__(16) char sA[128 * 64 * 2];
    __shared__ __align__(16) char sB[128 * 64 * 2];

    const int tid = threadIdx.x;
    const int lane = tid & 63;
    const int wid = tid >> 6;
    const int wm = wid >> 1, wn = wid & 1;
    const int row0 = blockIdx.y * 128;
    const int col0 = blockIdx.x * 128;

    f32x4 acc[4][4] = {};

    for (int k0 = 0; k0 < K; k0 += 64) {
        __syncthreads();  // prior tile consumed
        #pragma unroll
        for (int i = 0; i < 4; ++i) {
            int cid = i * 256 + tid;
            int row = cid >> 3, c2 = cid & 7;
            g2l16(&A[(size_t)(row0 + row) * K + k0 + ((c2 ^ (row & 7)) << 3)],
                  sA + ((i * 256 + (tid & 192)) << 4));
        }
        #pragma unroll
        for (int i = 0; i < 4; ++i) {
            int cid = i * 256 + tid;
            int row = cid >> 3, c2 = cid & 7;
            g2l16(&BT[(size_t)(col0 + row) * K + k0 + ((c2 ^ (row & 7)) << 3)],
                  sB + ((i * 256 + (tid & 192)) << 4));
        }
        __syncthreads();  // drains vmcnt -> tiles visible

        #pragma unroll
        for (int ks = 0; ks < 2; ++ks) {
            bf16x8 af[4], bf[4];
            #pragma unroll
            for (int mi = 0; mi < 4; ++mi) {
                int row = wm * 64 + mi * 16 + (lane & 15);
                int ch = ((lane >> 4) + 4 * ks) ^ (row & 7);
                af[mi] = *(const bf16x8*)(sA + row * 128 + (ch << 4));
            }
            #pragma unroll
            for (int ni = 0; ni < 4; ++ni) {
                int row = wn * 64 + ni * 16 + (lane & 15);
                int ch = ((lane >> 4) + 4 * ks) ^ (row & 7);
                bf[ni] = *(const bf16x8*)(sB + row * 128 + (ch << 4));
            }
            #pragma unroll
            for (int mi = 0; mi < 4; ++mi)
                #pragma unroll
                for (int ni = 0; ni < 4; ++ni)
                    acc[mi][ni] = __builtin_amdgcn_mfma_f32_16x16x32_bf16(
                        af[mi], bf[ni], acc[mi][ni], 0, 0, 0);
        }
    }

    // epilogue: C/D layout col=lane&15, row=(lane>>4)*4+reg
    #pragma unroll
    for (int mi = 0; mi < 4; ++mi) {
        const int rg = row0 + wm * 64 + mi * 16 + (lane >> 4) * 4;
        #pragma unroll
        for (int ni = 0; ni < 4; ++ni) {
            const int cg = col0 + wn * 64 + ni * 16 + (lane & 15);
            const float bv = bias[cg];
            if (EPI == 1) {
                #pragma unroll
                for (int r = 0; r < 4; ++r)
                    fo[(size_t)(rg + r) * N + cg] = acc[mi][ni][r] + bv;
            } else {
                const int region = col0 >> 10;  // uniform per block
                if (region < 2) {
                    unsigned short* dst = region ? ko : qo;
                    const int nn = cg - (region << 10);
                    #pragma unroll
                    for (int r = 0; r < 4; ++r)
                        dst[(size_t)(rg + r) * CEMB + nn] = f2bf(acc[mi][ni][r] + bv);
                } else {
                    const int nloc = cg - 2048;
                    const int h = nloc >> 6, d = nloc & 63;
                    const int b = rg >> 11, t = rg & 2047;
                    ushort4 pk;
                    pk.x = f2bf(acc[mi][ni][0] + bv);
                    pk.y = f2bf(acc[mi][ni][1] + bv);
                    pk.z = f2bf(acc[mi][ni][2] + bv);
                    pk.w = f2bf(acc[mi][ni][3] + bv);
                    *(ushort4*)&vo[(((size_t)b * NHEAD + h) * HDIM + d) * TSEQ + t] = pk;
                }
            }
        }
    }
}

// ---------------------------------------------------------------------------
// MFMA flash attention. Block = 256 threads (4 waves), one (b,h), 64 q-rows.
// Wave w owns q-rows w*16..w*16+15. K-tiles of 64 keys; online softmax in
// registers (rows live in C/D layout; row-reduce via 16-lane shfl_xor).
// qb/kb: bf16 [B*T][C] (head h at col h*64). vt: bf16 [b][h][d=64][t=2048].
// ob: bf16 [B*T][C].
// ---------------------------------------------------------------------------
__global__ __launch_bounds__(256) void flash_mfma(
    const unsigned short* __restrict__ qb, const unsigned short* __restrict__ kb,
    const unsigned short* __restrict__ vt, unsigned short* __restrict__ ob)
{
    const int u = blockIdx.x >> 5;
    const int bh = blockIdx.x & 31;
    const int qt = (u & 1) ? (31 - (u >> 1)) : (u >> 1);  // long/short interleave
    const int b = bh >> 4, h = bh & 15;
    const int q0 = qt * 64;

    __shared__ __align__(16) char sQ[8192];
    __shared__ __align__(16) char sK[8192];
    __shared__ __align__(16) char sV[8192];
    __shared__ __align__(16) char sP[8192];

    const int tid = threadIdx.x;
    const int lane = tid & 63;
    const int wid = tid >> 6;

    // stage Q (swizzled source)
    #pragma unroll
    for (int i = 0; i < 2; ++i) {
        int cid = i * 256 + tid;
        int row = cid >> 3, c2 = cid & 7;
        g2l16(&qb[(size_t)(b * TSEQ + q0 + row) * CEMB + h * HDIM + ((c2 ^ (row & 7)) << 3)],
              sQ + ((i * 256 + (tid & 192)) << 4));
    }

    f32x4 o[4] = {};
    float m[4], l[4];
    #pragma unroll
    for (int r = 0; r < 4; ++r) { m[r] = -INFINITY; l[r] = 0.f; }
    const float scale = 0.03125f;  // 1/sqrt(1024)

    for (int kt = 0; kt <= qt; ++kt) {
        const int k0 = kt * 64;
        __syncthreads();  // prev K/V consumed (first iter: drains Q stage)
        #pragma unroll
        for (int i = 0; i < 2; ++i) {
            int cid = i * 256 + tid;
            int row = cid >> 3, c2 = cid & 7;
            g2l16(&kb[(size_t)(b * TSEQ + k0 + row) * CEMB + h * HDIM + ((c2 ^ (row & 7)) << 3)],
                  sK + ((i * 256 + (tid & 192)) << 4));
        }
        #pragma unroll
        for (int i = 0; i < 2; ++i) {
            int cid = i * 256 + tid;
            int row = cid >> 3, c2 = cid & 7;  // row = d
            g2l16(&vt[(((size_t)b * NHEAD + h) * HDIM + row) * TSEQ + k0 + ((c2 ^ (row & 7)) << 3)],
                  sV + ((i * 256 + (tid & 192)) << 4));
        }
        __syncthreads();  // tiles visible

        // S = Q K^T (rows: this wave's 16 q-rows; cols: 64 keys)
        bf16x8 qf[2];
        #pragma unroll
        for (int ks = 0; ks < 2; ++ks) {
            int row = wid * 16 + (lane & 15);
            int ch = ((lane >> 4) + 4 * ks) ^ (row & 7);
            qf[ks] = *(const bf16x8*)(sQ + row * 128 + (ch << 4));
        }
        f32x4 s[4] = {};
        #pragma unroll
        for (int ni = 0; ni < 4; ++ni) {
            #pragma unroll
            for (int ks = 0; ks < 2; ++ks) {
                int row = ni * 16 + (lane & 15);
                int ch = ((lane >> 4) + 4 * ks) ^ (row & 7);
                bf16x8 kf = *(const bf16x8*)(sK + row * 128 + (ch << 4));
                s[ni] = __builtin_amdgcn_mfma_f32_16x16x32_bf16(qf[ks], kf, s[ni], 0, 0, 0);
            }
        }

        // scale + causal mask (diagonal tile only)
        #pragma unroll
        for (int ni = 0; ni < 4; ++ni)
            #pragma unroll
            for (int r = 0; r < 4; ++r)
                s[ni][r] *= scale;
        if (kt == qt) {
            #pragma unroll
            for (int ni = 0; ni < 4; ++ni) {
                const int colg = k0 + ni * 16 + (lane & 15);
                #pragma unroll
                for (int r = 0; r < 4; ++r) {
                    const int rowg = q0 + wid * 16 + (lane >> 4) * 4 + r;
                    if (colg > rowg) s[ni][r] = -INFINITY;
                }
            }
        }

        // online softmax per row (rows replicated across the 16 lanes of l>>4 group)
        #pragma unroll
        for (int r = 0; r < 4; ++r) {
            float v = fmaxf(fmaxf(s[0][r], s[1][r]), fmaxf(s[2][r], s[3][r]));
            v = fmaxf(v, __shfl_xor(v, 1));
            v = fmaxf(v, __shfl_xor(v, 2));
            v = fmaxf(v, __shfl_xor(v, 4));
            v = fmaxf(v, __shfl_xor(v, 8));
            const float mnew = fmaxf(m[r], v);
            const float sc = __expf(m[r] - mnew);
            m[r] = mnew;
            float ps = 0.f;
            #pragma unroll
            for (int ni = 0; ni < 4; ++ni) {
                const float p = __expf(s[ni][r] - mnew);
                s[ni][r] = p;
                ps += p;
            }
            ps += __shfl_xor(ps, 1);
            ps += __shfl_xor(ps, 2);
            ps += __shfl_xor(ps, 4);
            ps += __shfl_xor(ps, 8);
            l[r] = l[r] * sc + ps;
            #pragma unroll
            for (int ni = 0; ni < 4; ++ni)
                o[ni][r] *= sc;
        }

        // write P (bf16, swizzled) to this wave's 16-row stripe of sP
        #pragma unroll
        for (int ni = 0; ni < 4; ++ni) {
            #pragma unroll
            for (int r = 0; r < 4; ++r) {
                const int prow = wid * 16 + (lane >> 4) * 4 + r;
                const int pcol = ni * 16 + (lane & 15);
                const int byte = prow * 128 + ((((pcol >> 3) ^ (prow & 7))) << 4) + ((pcol & 7) << 1);
                *(unsigned short*)(sP + byte) = f2bf(s[ni][r]);
            }
        }
        asm volatile("s_waitcnt lgkmcnt(0)" ::: "memory");  // wave-local P visible

        // O += P @ V
        bf16x8 pf[2];
        #pragma unroll
        for (int ks = 0; ks < 2; ++ks) {
            int row = wid * 16 + (lane & 15);
            int ch = ((lane >> 4) + 4 * ks) ^ (row & 7);
            pf[ks] = *(const bf16x8*)(sP + row * 128 + (ch << 4));
        }
        #pragma unroll
        for (int ni = 0; ni < 4; ++ni) {
            #pragma unroll
            for (int ks = 0; ks < 2; ++ks) {
                int row = ni * 16 + (lane & 15);  // d row of V^T
                int ch = ((lane >> 4) + 4 * ks) ^ (row & 7);
                bf16x8 vf = *(const bf16x8*)(sV + row * 128 + (ch << 4));
                o[ni] = __builtin_amdgcn_mfma_f32_16x16x32_bf16(pf[ks], vf, o[ni], 0, 0, 0);
            }
        }
    }

    // normalize + store
    float linv[4];
    #pragma unroll
    for (int r = 0; r < 4; ++r) linv[r] = 1.f / l[r];
    #pragma unroll
    for (int ni = 0; ni < 4; ++ni) {
        #pragma unroll
        for (int r = 0; r < 4; ++r) {
            const int rowt = q0 + wid * 16 + (lane >> 4) * 4 + r;
            const int col = h * HDIM + ni * 16 + (lane & 15);
            ob[(size_t)(b * TSEQ + rowt) * CEMB + col] = f2bf(o[ni][r] * linv[r]);
        }
    }
}

// ---------------------------------------------------------------------------
extern "C" void kernel_launch(void* const* d_in, const int* in_sizes, int n_in,
                              void* d_out, int out_size, void* d_ws, size_t ws_size,
                              hipStream_t stream)
{
    (void)in_sizes; (void)n_in; (void)out_size; (void)ws_size;

    const float* x      = (const float*)d_in[0];
    const float* w_qkv  = (const float*)d_in[1];
    const float* b_qkv  = (const float*)d_in[2];
    const float* w_proj = (const float*)d_in[3];
    const float* b_proj = (const float*)d_in[4];
    float* out = (float*)d_out;

    const int M = BSZ * TSEQ;  // 4096
    unsigned short* xb     = (unsigned short*)d_ws;           // [4096][1024]
    unsigned short* wqkvT  = xb     + (size_t)M * CEMB;       // [3072][1024]
    unsigned short* wprojT = wqkvT  + (size_t)3 * CEMB * CEMB;// [1024][1024]
    unsigned short* qbuf   = wprojT + (size_t)CEMB * CEMB;    // [4096][1024]
    unsigned short* kbuf   = qbuf   + (size_t)M * CEMB;       // [4096][1024]
    unsigned short* vbuf   = kbuf   + (size_t)M * CEMB;       // [2][16][64][2048]
    unsigned short* attb   = vbuf   + (size_t)M * CEMB;       // [4096][1024]

    conv_f32_bf16<<<dim3((M * CEMB) / 2048), 256, 0, stream>>>(x, xb);
    conv_transpose_bf16<<<dim3(3 * CEMB / 32, CEMB / 32), 256, 0, stream>>>(
        w_qkv, wqkvT, CEMB, 3 * CEMB);
    conv_transpose_bf16<<<dim3(CEMB / 32, CEMB / 32), 256, 0, stream>>>(
        w_proj, wprojT, CEMB, CEMB);

    gemm_mfma<0><<<dim3(3 * CEMB / 128, M / 128), 256, 0, stream>>>(
        xb, wqkvT, b_qkv, qbuf, kbuf, vbuf, nullptr, M, 3 * CEMB, CEMB);

    flash_mfma<<<dim3(32 * 32), 256, 0, stream>>>(qbuf, kbuf, vbuf, attb);

    gemm_mfma<1><<<dim3(CEMB / 128, M / 128), 256, 0, stream>>>(
        attb, wprojT, b_proj, nullptr, nullptr, nullptr, out, M, CEMB, CEMB);
}

// Round 8
// 196.314 us; speedup vs baseline: 10.2209x; 1.0774x over previous
//
#include <hip/hip_runtime.h>
#include <math.h>

#define BSZ 2
#define TSEQ 2048
#define CEMB 1024
#define NHEAD 16
#define HDIM 64

typedef float f32x4 __attribute__((ext_vector_type(4)));
typedef short bf16x8 __attribute__((ext_vector_type(8)));

typedef __attribute__((address_space(3))) char lds_char;
typedef __attribute__((address_space(1))) const char gbl_char;

__device__ __forceinline__ void g2l16(const void* g, void* l) {
    // async global->LDS, 16B per lane; LDS dest = wave-uniform base + lane*16
    __builtin_amdgcn_global_load_lds((const gbl_char*)g, (lds_char*)l, 16, 0, 0);
}

__device__ __forceinline__ unsigned short f2bf(float x) {
    unsigned u = __float_as_uint(x);
    unsigned r = ((u >> 16) & 1u) + 0x7fffu;   // round-to-nearest-even
    return (unsigned short)((u + r) >> 16);
}

// ---------------------------------------------------------------------------
// fp32 -> bf16 elementwise (8 elems/thread, 16B stores)
// ---------------------------------------------------------------------------
__global__ __launch_bounds__(256) void conv_f32_bf16(
    const float* __restrict__ in, unsigned short* __restrict__ out)
{
    size_t i = ((size_t)blockIdx.x * 256 + threadIdx.x) * 8;
    float4 a = *(const float4*)(in + i);
    float4 b = *(const float4*)(in + i + 4);
    union { unsigned short u[8]; uint4 v; } pk;
    pk.u[0] = f2bf(a.x); pk.u[1] = f2bf(a.y); pk.u[2] = f2bf(a.z); pk.u[3] = f2bf(a.w);
    pk.u[4] = f2bf(b.x); pk.u[5] = f2bf(b.y); pk.u[6] = f2bf(b.z); pk.u[7] = f2bf(b.w);
    *(uint4*)(out + i) = pk.v;
}

// ---------------------------------------------------------------------------
// fp32 [K][N] -> bf16 transposed [N][K]
// ---------------------------------------------------------------------------
__global__ __launch_bounds__(256) void conv_transpose_bf16(
    const float* __restrict__ w, unsigned short* __restrict__ wT, int K, int N)
{
    __shared__ float t[32][33];
    const int n0 = blockIdx.x * 32, k0 = blockIdx.y * 32;
    const int tx = threadIdx.x & 31, ty = threadIdx.x >> 5;  // 32 x 8
    #pragma unroll
    for (int i = 0; i < 4; ++i)
        t[ty + i * 8][tx] = w[(size_t)(k0 + ty + i * 8) * N + n0 + tx];
    __syncthreads();
    #pragma unroll
    for (int i = 0; i < 4; ++i) {
        int r = ty + i * 8;
        wT[(size_t)(n0 + r) * K + k0 + tx] = f2bf(t[tx][r]);
    }
}

// ---------------------------------------------------------------------------
// bf16 MFMA GEMM: C[M,N] = A[M,K] @ BT[N,K]^T + bias  (unchanged from R1)
// ---------------------------------------------------------------------------
template <int EPI>
__global__ __launch_bounds__(256) void gemm_mfma(
    const unsigned short* __restrict__ A, const unsigned short* __restrict__ BT,
    const float* __restrict__ bias,
    unsigned short* __restrict__ qo, unsigned short* __restrict__ ko,
    unsigned short* __restrict__ vo, float* __restrict__ fo,
    int M, int N, int K)
{
    __shared__ __align__(16) char sA[128 * 64 * 2];
    __shared__ __align__(16) char sB[128 * 64 * 2];

    const int tid = threadIdx.x;
    const int lane = tid & 63;
    const int wid = tid >> 6;
    const int wm = wid >> 1, wn = wid & 1;
    const int row0 = blockIdx.y * 128;
    const int col0 = blockIdx.x * 128;

    f32x4 acc[4][4] = {};

    for (int k0 = 0; k0 < K; k0 += 64) {
        __syncthreads();
        #pragma unroll
        for (int i = 0; i < 4; ++i) {
            int cid = i * 256 + tid;
            int row = cid >> 3, c2 = cid & 7;
            g2l16(&A[(size_t)(row0 + row) * K + k0 + ((c2 ^ (row & 7)) << 3)],
                  sA + ((i * 256 + (tid & 192)) << 4));
        }
        #pragma unroll
        for (int i = 0; i < 4; ++i) {
            int cid = i * 256 + tid;
            int row = cid >> 3, c2 = cid & 7;
            g2l16(&BT[(size_t)(col0 + row) * K + k0 + ((c2 ^ (row & 7)) << 3)],
                  sB + ((i * 256 + (tid & 192)) << 4));
        }
        __syncthreads();

        #pragma unroll
        for (int ks = 0; ks < 2; ++ks) {
            bf16x8 af[4], bf[4];
            #pragma unroll
            for (int mi = 0; mi < 4; ++mi) {
                int row = wm * 64 + mi * 16 + (lane & 15);
                int ch = ((lane >> 4) + 4 * ks) ^ (row & 7);
                af[mi] = *(const bf16x8*)(sA + row * 128 + (ch << 4));
            }
            #pragma unroll
            for (int ni = 0; ni < 4; ++ni) {
                int row = wn * 64 + ni * 16 + (lane & 15);
                int ch = ((lane >> 4) + 4 * ks) ^ (row & 7);
                bf[ni] = *(const bf16x8*)(sB + row * 128 + (ch << 4));
            }
            #pragma unroll
            for (int mi = 0; mi < 4; ++mi)
                #pragma unroll
                for (int ni = 0; ni < 4; ++ni)
                    acc[mi][ni] = __builtin_amdgcn_mfma_f32_16x16x32_bf16(
                        af[mi], bf[ni], acc[mi][ni], 0, 0, 0);
        }
    }

    #pragma unroll
    for (int mi = 0; mi < 4; ++mi) {
        const int rg = row0 + wm * 64 + mi * 16 + (lane >> 4) * 4;
        #pragma unroll
        for (int ni = 0; ni < 4; ++ni) {
            const int cg = col0 + wn * 64 + ni * 16 + (lane & 15);
            const float bv = bias[cg];
            if (EPI == 1) {
                #pragma unroll
                for (int r = 0; r < 4; ++r)
                    fo[(size_t)(rg + r) * N + cg] = acc[mi][ni][r] + bv;
            } else {
                const int region = col0 >> 10;
                if (region < 2) {
                    unsigned short* dst = region ? ko : qo;
                    const int nn = cg - (region << 10);
                    #pragma unroll
                    for (int r = 0; r < 4; ++r)
                        dst[(size_t)(rg + r) * CEMB + nn] = f2bf(acc[mi][ni][r] + bv);
                } else {
                    const int nloc = cg - 2048;
                    const int h = nloc >> 6, d = nloc & 63;
                    const int b = rg >> 11, t = rg & 2047;
                    ushort4 pk;
                    pk.x = f2bf(acc[mi][ni][0] + bv);
                    pk.y = f2bf(acc[mi][ni][1] + bv);
                    pk.z = f2bf(acc[mi][ni][2] + bv);
                    pk.w = f2bf(acc[mi][ni][3] + bv);
                    *(ushort4*)&vo[(((size_t)b * NHEAD + h) * HDIM + d) * TSEQ + t] = pk;
                }
            }
        }
    }
}

// ---------------------------------------------------------------------------
// MFMA flash attention, SWAPPED QK^T form.
// S^T = mfma(K, Q): per lane qrow = lane&15 (one row), keys = 16*ni+4*g+r.
// Row softmax = 15 in-lane ops + 2 shfl_xor (vs 32 shfls before).
// O^T = mfma(V^T, P^T) accumulates [d][qrow]; epilogue transposes via sP.
// exp2 domain (scale = log2e/32 folded) + defer-max (THR=8, P <= 2^8).
// ---------------------------------------------------------------------------
__global__ __launch_bounds__(256) void flash_mfma(
    const unsigned short* __restrict__ qb, const unsigned short* __restrict__ kb,
    const unsigned short* __restrict__ vt, unsigned short* __restrict__ ob)
{
    const int u = blockIdx.x >> 5;
    const int bh = blockIdx.x & 31;
    const int qt = (u & 1) ? (31 - (u >> 1)) : (u >> 1);  // long/short interleave
    const int b = bh >> 4, h = bh & 15;
    const int q0 = qt * 64;

    __shared__ __align__(16) char sQ[8192];
    __shared__ __align__(16) char sK[8192];
    __shared__ __align__(16) char sV[8192];
    __shared__ __align__(16) char sP[8192];

    const int tid = threadIdx.x;
    const int lane = tid & 63;
    const int wid = tid >> 6;
    const int g = lane >> 4;       // lane group 0..3
    const int lr = lane & 15;      // this lane's q-row within the wave stripe
    const int q7 = lr & 7;         // row&7 for swizzle (rows are 16-aligned)

    // stage Q (swizzled source, linear LDS dest)
    #pragma unroll
    for (int i = 0; i < 2; ++i) {
        int cid = i * 256 + tid;
        int row = cid >> 3, c2 = cid & 7;
        g2l16(&qb[(size_t)(b * TSEQ + q0 + row) * CEMB + h * HDIM + ((c2 ^ (row & 7)) << 3)],
              sQ + ((i * 256 + (tid & 192)) << 4));
    }

    f32x4 o[4] = {};                 // O^T: o[ni][r] = O[d=16ni+4g+r][qrow]
    float mrow = -INFINITY, lrow = 0.f;
    const float c = 0.0450744431f;   // log2(e)/32  (exp2 domain)

    for (int kt = 0; kt <= qt; ++kt) {
        const int k0 = kt * 64;
        __syncthreads();  // prev K/V consumed (first iter: Q stage ordered too)
        #pragma unroll
        for (int i = 0; i < 2; ++i) {
            int cid = i * 256 + tid;
            int row = cid >> 3, c2 = cid & 7;
            g2l16(&kb[(size_t)(b * TSEQ + k0 + row) * CEMB + h * HDIM + ((c2 ^ (row & 7)) << 3)],
                  sK + ((i * 256 + (tid & 192)) << 4));
        }
        #pragma unroll
        for (int i = 0; i < 2; ++i) {
            int cid = i * 256 + tid;
            int row = cid >> 3, c2 = cid & 7;  // row = d
            g2l16(&vt[(((size_t)b * NHEAD + h) * HDIM + row) * TSEQ + k0 + ((c2 ^ (row & 7)) << 3)],
                  sV + ((i * 256 + (tid & 192)) << 4));
        }
        __syncthreads();  // tiles visible

        // S^T = K Q^T : s[ni] rows = keys 16ni+4g+r, col = qrow (lane&15)
        bf16x8 qf[2];
        #pragma unroll
        for (int ks = 0; ks < 2; ++ks) {
            int row = wid * 16 + lr;
            int ch = (g + 4 * ks) ^ q7;
            qf[ks] = *(const bf16x8*)(sQ + row * 128 + (ch << 4));
        }
        f32x4 s[4] = {};
        #pragma unroll
        for (int ni = 0; ni < 4; ++ni) {
            #pragma unroll
            for (int ks = 0; ks < 2; ++ks) {
                int row = ni * 16 + lr;
                int ch = (g + 4 * ks) ^ q7;
                bf16x8 kf = *(const bf16x8*)(sK + row * 128 + (ch << 4));
                s[ni] = __builtin_amdgcn_mfma_f32_16x16x32_bf16(kf, qf[ks], s[ni], 0, 0, 0);
            }
        }

        // scale into exp2 domain + causal mask (diag tile only)
        #pragma unroll
        for (int ni = 0; ni < 4; ++ni)
            #pragma unroll
            for (int r = 0; r < 4; ++r)
                s[ni][r] *= c;
        const int qrow_g = q0 + wid * 16 + lr;
        if (kt == qt) {
            #pragma unroll
            for (int ni = 0; ni < 4; ++ni)
                #pragma unroll
                for (int r = 0; r < 4; ++r)
                    if (k0 + ni * 16 + g * 4 + r > qrow_g) s[ni][r] = -INFINITY;
        }

        // row max: 15 in-lane + 2 shfl (xor 16, 32 crosses the 4 lane-groups)
        f32x4 m01, m23;
        #pragma unroll
        for (int r = 0; r < 4; ++r) {
            m01[r] = fmaxf(s[0][r], s[1][r]);
            m23[r] = fmaxf(s[2][r], s[3][r]);
        }
        float v = fmaxf(fmaxf(fmaxf(m01[0], m23[0]), fmaxf(m01[1], m23[1])),
                        fmaxf(fmaxf(m01[2], m23[2]), fmaxf(m01[3], m23[3])));
        v = fmaxf(v, __shfl_xor(v, 16));
        v = fmaxf(v, __shfl_xor(v, 32));

        // defer-max: only rescale when max grew by > 8 (exp2 domain, P <= 2^8)
        if (!__all(v <= mrow + 8.f)) {
            const float mnew = fmaxf(mrow, v);
            const float sc = exp2f(mrow - mnew);   // first tile: exp2(-inf)=0
            lrow *= sc;
            #pragma unroll
            for (int ni = 0; ni < 4; ++ni)
                #pragma unroll
                for (int r = 0; r < 4; ++r)
                    o[ni][r] *= sc;
            mrow = mnew;
        }

        // P = exp2(S - m); in-lane sum + 2 shfl; pack bf16 pairs -> ds_write_b64
        float ps = 0.f;
        #pragma unroll
        for (int ni = 0; ni < 4; ++ni) {
            ushort4 pk;
            #pragma unroll
            for (int r = 0; r < 4; ++r) {
                const float p = exp2f(s[ni][r] - mrow);
                ps += p;
                ((unsigned short*)&pk)[r] = f2bf(p);
            }
            // sP layout: P[qrow][key], qrow = wid*16+lr, keys 16ni+4g..+3
            const int ch = (2 * ni + (g >> 1)) ^ q7;
            *(uint2*)(sP + (wid * 16 + lr) * 128 + (ch << 4) + ((g & 1) << 3)) =
                *(const uint2*)&pk;
        }
        ps += __shfl_xor(ps, 16);
        ps += __shfl_xor(ps, 32);
        lrow += ps;

        asm volatile("s_waitcnt lgkmcnt(0)" ::: "memory");  // wave-local P visible

        // O^T += V^T P^T : A = V^T rows (d), B = P rows (qrow, along key)
        bf16x8 pf[2];
        #pragma unroll
        for (int ks = 0; ks < 2; ++ks) {
            int ch = (g + 4 * ks) ^ q7;
            pf[ks] = *(const bf16x8*)(sP + (wid * 16 + lr) * 128 + (ch << 4));
        }
        #pragma unroll
        for (int ni = 0; ni < 4; ++ni) {
            #pragma unroll
            for (int ks = 0; ks < 2; ++ks) {
                int row = ni * 16 + lr;            // d row of V^T
                int ch = (g + 4 * ks) ^ q7;
                bf16x8 vf = *(const bf16x8*)(sV + row * 128 + (ch << 4));
                o[ni] = __builtin_amdgcn_mfma_f32_16x16x32_bf16(vf, pf[ks], o[ni], 0, 0, 0);
            }
        }
    }

    // epilogue: normalize, write O^T into sP as [qrow][d] (swizzled), transpose-read
    const float linv = 1.f / lrow;
    __syncthreads();  // all waves done with their sP P-stripes
    #pragma unroll
    for (int ni = 0; ni < 4; ++ni) {
        ushort4 pk;
        #pragma unroll
        for (int r = 0; r < 4; ++r)
            ((unsigned short*)&pk)[r] = f2bf(o[ni][r] * linv);
        const int ch = (2 * ni + (g >> 1)) ^ q7;   // d = 16ni+4g+r -> d>>3 = 2ni+(g>>1)
        *(uint2*)(sP + (wid * 16 + lr) * 128 + (ch << 4) + ((g & 1) << 3)) =
            *(const uint2*)&pk;
    }
    __syncthreads();
    #pragma unroll
    for (int i = 0; i < 2; ++i) {
        const int cid = i * 256 + tid;
        const int row = cid >> 3;      // qrow 0..63
        const int ch = cid & 7;        // d-chunk
        uint4 val = *(const uint4*)(sP + row * 128 + ((ch ^ (row & 7)) << 4));
        *(uint4*)&ob[(size_t)(b * TSEQ + q0 + row) * CEMB + h * HDIM + ch * 8] = val;
    }
}

// ---------------------------------------------------------------------------
extern "C" void kernel_launch(void* const* d_in, const int* in_sizes, int n_in,
                              void* d_out, int out_size, void* d_ws, size_t ws_size,
                              hipStream_t stream)
{
    (void)in_sizes; (void)n_in; (void)out_size; (void)ws_size;

    const float* x      = (const float*)d_in[0];
    const float* w_qkv  = (const float*)d_in[1];
    const float* b_qkv  = (const float*)d_in[2];
    const float* w_proj = (const float*)d_in[3];
    const float* b_proj = (const float*)d_in[4];
    float* out = (float*)d_out;

    const int M = BSZ * TSEQ;  // 4096
    unsigned short* xb     = (unsigned short*)d_ws;           // [4096][1024]
    unsigned short* wqkvT  = xb     + (size_t)M * CEMB;       // [3072][1024]
    unsigned short* wprojT = wqkvT  + (size_t)3 * CEMB * CEMB;// [1024][1024]
    unsigned short* qbuf   = wprojT + (size_t)CEMB * CEMB;    // [4096][1024]
    unsigned short* kbuf   = qbuf   + (size_t)M * CEMB;       // [4096][1024]
    unsigned short* vbuf   = kbuf   + (size_t)M * CEMB;       // [2][16][64][2048]
    unsigned short* attb   = vbuf   + (size_t)M * CEMB;       // [4096][1024]

    conv_f32_bf16<<<dim3((M * CEMB) / 2048), 256, 0, stream>>>(x, xb);
    conv_transpose_bf16<<<dim3(3 * CEMB / 32, CEMB / 32), 256, 0, stream>>>(
        w_qkv, wqkvT, CEMB, 3 * CEMB);
    conv_transpose_bf16<<<dim3(CEMB / 32, CEMB / 32), 256, 0, stream>>>(
        w_proj, wprojT, CEMB, CEMB);

    gemm_mfma<0><<<dim3(3 * CEMB / 128, M / 128), 256, 0, stream>>>(
        xb, wqkvT, b_qkv, qbuf, kbuf, vbuf, nullptr, M, 3 * CEMB, CEMB);

    flash_mfma<<<dim3(32 * 32), 256, 0, stream>>>(qbuf, kbuf, vbuf, attb);

    gemm_mfma<1><<<dim3(CEMB / 128, M / 128), 256, 0, stream>>>(
        attb, wprojT, b_proj, nullptr, nullptr, nullptr, out, M, CEMB, CEMB);
}

// Round 10
// 188.038 us; speedup vs baseline: 10.6708x; 1.0440x over previous
//
#include <hip/hip_runtime.h>
#include <math.h>

#define BSZ 2
#define TSEQ 2048
#define CEMB 1024
#define NHEAD 16
#define HDIM 64

typedef float f32x4 __attribute__((ext_vector_type(4)));
typedef short bf16x8 __attribute__((ext_vector_type(8)));

typedef __attribute__((address_space(3))) char lds_char;
typedef __attribute__((address_space(1))) const char gbl_char;

__device__ __forceinline__ void g2l16(const void* g, void* l) {
    // async global->LDS, 16B per lane; LDS dest = wave-uniform base + lane*16
    __builtin_amdgcn_global_load_lds((const gbl_char*)g, (lds_char*)l, 16, 0, 0);
}

__device__ __forceinline__ unsigned short f2bf(float x) {
    unsigned u = __float_as_uint(x);
    unsigned r = ((u >> 16) & 1u) + 0x7fffu;   // round-to-nearest-even
    return (unsigned short)((u + r) >> 16);
}

__device__ __forceinline__ unsigned pkbf(float lo, float hi) {
    // 2x f32 -> packed 2x bf16 in one VALU op (guide T12 recipe; no builtin)
    unsigned r;
    asm("v_cvt_pk_bf16_f32 %0, %1, %2" : "=v"(r) : "v"(lo), "v"(hi));
    return r;
}

// ---------------------------------------------------------------------------
// fp32 -> bf16 elementwise (8 elems/thread, 16B stores)
// ---------------------------------------------------------------------------
__global__ __launch_bounds__(256) void conv_f32_bf16(
    const float* __restrict__ in, unsigned short* __restrict__ out)
{
    size_t i = ((size_t)blockIdx.x * 256 + threadIdx.x) * 8;
    float4 a = *(const float4*)(in + i);
    float4 b = *(const float4*)(in + i + 4);
    union { unsigned short u[8]; uint4 v; } pk;
    pk.u[0] = f2bf(a.x); pk.u[1] = f2bf(a.y); pk.u[2] = f2bf(a.z); pk.u[3] = f2bf(a.w);
    pk.u[4] = f2bf(b.x); pk.u[5] = f2bf(b.y); pk.u[6] = f2bf(b.z); pk.u[7] = f2bf(b.w);
    *(uint4*)(out + i) = pk.v;
}

// ---------------------------------------------------------------------------
// fp32 [K][N] -> bf16 transposed [N][K]
// ---------------------------------------------------------------------------
__global__ __launch_bounds__(256) void conv_transpose_bf16(
    const float* __restrict__ w, unsigned short* __restrict__ wT, int K, int N)
{
    __shared__ float t[32][33];
    const int n0 = blockIdx.x * 32, k0 = blockIdx.y * 32;
    const int tx = threadIdx.x & 31, ty = threadIdx.x >> 5;  // 32 x 8
    #pragma unroll
    for (int i = 0; i < 4; ++i)
        t[ty + i * 8][tx] = w[(size_t)(k0 + ty + i * 8) * N + n0 + tx];
    __syncthreads();
    #pragma unroll
    for (int i = 0; i < 4; ++i) {
        int r = ty + i * 8;
        wT[(size_t)(n0 + r) * K + k0 + tx] = f2bf(t[tx][r]);
    }
}

// ---------------------------------------------------------------------------
// bf16 MFMA GEMM: C[M,N] = A[M,K] @ BT[N,K]^T + bias
// EPI=0: QKV epilogue (Q pre-scaled by log2e/32, K bf16, V transposed).
// EPI=1: fp32 out + bias.
// ---------------------------------------------------------------------------
template <int EPI>
__global__ __launch_bounds__(256) void gemm_mfma(
    const unsigned short* __restrict__ A, const unsigned short* __restrict__ BT,
    const float* __restrict__ bias,
    unsigned short* __restrict__ qo, unsigned short* __restrict__ ko,
    unsigned short* __restrict__ vo, float* __restrict__ fo,
    int M, int N, int K)
{
    __shared__ __align__(16) char sA[128 * 64 * 2];
    __shared__ __align__(16) char sB[128 * 64 * 2];

    const int tid = threadIdx.x;
    const int lane = tid & 63;
    const int wid = tid >> 6;
    const int wm = wid >> 1, wn = wid & 1;
    const int row0 = blockIdx.y * 128;
    const int col0 = blockIdx.x * 128;

    f32x4 acc[4][4] = {};

    for (int k0 = 0; k0 < K; k0 += 64) {
        __syncthreads();
        #pragma unroll
        for (int i = 0; i < 4; ++i) {
            int cid = i * 256 + tid;
            int row = cid >> 3, c2 = cid & 7;
            g2l16(&A[(size_t)(row0 + row) * K + k0 + ((c2 ^ (row & 7)) << 3)],
                  sA + ((i * 256 + (tid & 192)) << 4));
        }
        #pragma unroll
        for (int i = 0; i < 4; ++i) {
            int cid = i * 256 + tid;
            int row = cid >> 3, c2 = cid & 7;
            g2l16(&BT[(size_t)(col0 + row) * K + k0 + ((c2 ^ (row & 7)) << 3)],
                  sB + ((i * 256 + (tid & 192)) << 4));
        }
        __syncthreads();

        #pragma unroll
        for (int ks = 0; ks < 2; ++ks) {
            bf16x8 af[4], bf[4];
            #pragma unroll
            for (int mi = 0; mi < 4; ++mi) {
                int row = wm * 64 + mi * 16 + (lane & 15);
                int ch = ((lane >> 4) + 4 * ks) ^ (row & 7);
                af[mi] = *(const bf16x8*)(sA + row * 128 + (ch << 4));
            }
            #pragma unroll
            for (int ni = 0; ni < 4; ++ni) {
                int row = wn * 64 + ni * 16 + (lane & 15);
                int ch = ((lane >> 4) + 4 * ks) ^ (row & 7);
                bf[ni] = *(const bf16x8*)(sB + row * 128 + (ch << 4));
            }
            #pragma unroll
            for (int mi = 0; mi < 4; ++mi)
                #pragma unroll
                for (int ni = 0; ni < 4; ++ni)
                    acc[mi][ni] = __builtin_amdgcn_mfma_f32_16x16x32_bf16(
                        af[mi], bf[ni], acc[mi][ni], 0, 0, 0);
        }
    }

    #pragma unroll
    for (int mi = 0; mi < 4; ++mi) {
        const int rg = row0 + wm * 64 + mi * 16 + (lane >> 4) * 4;
        #pragma unroll
        for (int ni = 0; ni < 4; ++ni) {
            const int cg = col0 + wn * 64 + ni * 16 + (lane & 15);
            const float bv = bias[cg];
            if (EPI == 1) {
                #pragma unroll
                for (int r = 0; r < 4; ++r)
                    fo[(size_t)(rg + r) * N + cg] = acc[mi][ni][r] + bv;
            } else {
                const int region = col0 >> 10;
                if (region < 2) {
                    unsigned short* dst = region ? ko : qo;
                    // fold softmax scale (in exp2 domain) into Q at the source
                    const float sc = region ? 1.f : 0.0450744431f;  // log2(e)/32
                    const int nn = cg - (region << 10);
                    #pragma unroll
                    for (int r = 0; r < 4; ++r)
                        dst[(size_t)(rg + r) * CEMB + nn] = f2bf((acc[mi][ni][r] + bv) * sc);
                } else {
                    const int nloc = cg - 2048;
                    const int h = nloc >> 6, d = nloc & 63;
                    const int b = rg >> 11, t = rg & 2047;
                    ushort4 pk;
                    pk.x = f2bf(acc[mi][ni][0] + bv);
                    pk.y = f2bf(acc[mi][ni][1] + bv);
                    pk.z = f2bf(acc[mi][ni][2] + bv);
                    pk.w = f2bf(acc[mi][ni][3] + bv);
                    *(ushort4*)&vo[(((size_t)b * NHEAD + h) * HDIM + d) * TSEQ + t] = pk;
                }
            }
        }
    }
}

// ---------------------------------------------------------------------------
// MFMA flash attention, swapped QK^T, double-buffered K/V, 1 barrier/tile.
// Block map: bid = (k<<8)|(bh<<3)|b; qt = (k&1)? 31-((b<<1)|(k>>1)) : (b<<1)|(k>>1)
//   -> per-CU (stride-256 dispatch) qt-sum == 66 exactly, same (b,h) per CU.
// Q pre-scaled by log2e/32 at the QKV GEMM -> S already in exp2 domain.
// ---------------------------------------------------------------------------
__global__ __launch_bounds__(256) void flash_mfma(
    const unsigned short* __restrict__ qb, const unsigned short* __restrict__ kb,
    const unsigned short* __restrict__ vt, unsigned short* __restrict__ ob)
{
    const int bid = blockIdx.x;
    const int k4 = bid >> 8;
    const int rem = bid & 255;
    const int bh = rem >> 3;
    const int bq = rem & 7;
    const int qt = (k4 & 1) ? (31 - ((bq << 1) | (k4 >> 1)))
                            : ((bq << 1) | (k4 >> 1));
    const int b = bh >> 4, h = bh & 15;
    const int q0 = qt * 64;

    __shared__ __align__(16) char sK[2][8192];
    __shared__ __align__(16) char sV[2][8192];
    __shared__ __align__(16) char sP[8192];

    const int tid = threadIdx.x;
    const int lane = tid & 63;
    const int wid = tid >> 6;
    const int g = lane >> 4;       // lane group 0..3
    const int lr = lane & 15;      // this lane's q-row within the wave stripe
    const int q7 = lr & 7;

    // stage Q (via sP) + K/V tile 0 (buf 0)
    #pragma unroll
    for (int i = 0; i < 2; ++i) {
        int cid = i * 256 + tid;
        int row = cid >> 3, c2 = cid & 7;
        g2l16(&qb[(size_t)(b * TSEQ + q0 + row) * CEMB + h * HDIM + ((c2 ^ (row & 7)) << 3)],
              sP + ((i * 256 + (tid & 192)) << 4));
        g2l16(&kb[(size_t)(b * TSEQ + row) * CEMB + h * HDIM + ((c2 ^ (row & 7)) << 3)],
              sK[0] + ((i * 256 + (tid & 192)) << 4));
        g2l16(&vt[(((size_t)b * NHEAD + h) * HDIM + row) * TSEQ + ((c2 ^ (row & 7)) << 3)],
              sV[0] + ((i * 256 + (tid & 192)) << 4));
    }
    __syncthreads();   // drain all staging

    // Q fragments: loop-invariant, held in registers
    bf16x8 qf[2];
    #pragma unroll
    for (int ks = 0; ks < 2; ++ks) {
        int ch = (g + 4 * ks) ^ q7;
        qf[ks] = *(const bf16x8*)(sP + (wid * 16 + lr) * 128 + (ch << 4));
    }
    __syncthreads();   // all waves have Q before sP becomes the P buffer

    f32x4 o[4] = {};                 // O^T: o[ni][r] = O[d=16ni+4g+r][qrow]
    float mrow = -INFINITY, lrow = 0.f;
    const int qrow_g = q0 + wid * 16 + lr;

    for (int kt = 0; kt <= qt; ++kt) {
        const int cur = kt & 1;

        // prefetch next K/V while this tile computes (drained at end-of-tile sync)
        if (kt < qt) {
            const int k0n = (kt + 1) * 64;
            const int nxt = cur ^ 1;
            #pragma unroll
            for (int i = 0; i < 2; ++i) {
                int cid = i * 256 + tid;
                int row = cid >> 3, c2 = cid & 7;
                g2l16(&kb[(size_t)(b * TSEQ + k0n + row) * CEMB + h * HDIM + ((c2 ^ (row & 7)) << 3)],
                      sK[nxt] + ((i * 256 + (tid & 192)) << 4));
                g2l16(&vt[(((size_t)b * NHEAD + h) * HDIM + row) * TSEQ + k0n + ((c2 ^ (row & 7)) << 3)],
                      sV[nxt] + ((i * 256 + (tid & 192)) << 4));
            }
        }

        // S^T = K Q^T : s[ni][r] = S[key=16ni+4g+r][qrow=lr] (exp2 domain)
        f32x4 s[4] = {};
        #pragma unroll
        for (int ni = 0; ni < 4; ++ni) {
            #pragma unroll
            for (int ks = 0; ks < 2; ++ks) {
                int row = ni * 16 + lr;
                int ch = (g + 4 * ks) ^ q7;
                bf16x8 kf = *(const bf16x8*)(sK[cur] + row * 128 + (ch << 4));
                s[ni] = __builtin_amdgcn_mfma_f32_16x16x32_bf16(kf, qf[ks], s[ni], 0, 0, 0);
            }
        }

        // causal mask (diagonal tile only)
        if (kt == qt) {
            const int k0 = kt * 64;
            #pragma unroll
            for (int ni = 0; ni < 4; ++ni)
                #pragma unroll
                for (int r = 0; r < 4; ++r)
                    if (k0 + ni * 16 + g * 4 + r > qrow_g) s[ni][r] = -INFINITY;
        }

        // row max: linear fmax chain (fuses to v_max3) + 2 shfl
        float v = s[0][0];
        v = fmaxf(v, s[0][1]); v = fmaxf(v, s[0][2]); v = fmaxf(v, s[0][3]);
        v = fmaxf(v, s[1][0]); v = fmaxf(v, s[1][1]); v = fmaxf(v, s[1][2]); v = fmaxf(v, s[1][3]);
        v = fmaxf(v, s[2][0]); v = fmaxf(v, s[2][1]); v = fmaxf(v, s[2][2]); v = fmaxf(v, s[2][3]);
        v = fmaxf(v, s[3][0]); v = fmaxf(v, s[3][1]); v = fmaxf(v, s[3][2]); v = fmaxf(v, s[3][3]);
        v = fmaxf(v, __shfl_xor(v, 16));
        v = fmaxf(v, __shfl_xor(v, 32));

        // defer-max: rescale only when max grew by > 8 (P <= 2^8)
        if (!__all(v <= mrow + 8.f)) {
            const float mnew = fmaxf(mrow, v);
            const float sc = exp2f(mrow - mnew);   // first tile: exp2(-inf)=0
            lrow *= sc;
            #pragma unroll
            for (int ni = 0; ni < 4; ++ni)
                #pragma unroll
                for (int r = 0; r < 4; ++r)
                    o[ni][r] *= sc;
            mrow = mnew;
        }

        // P = exp2(S - m); pack via v_cvt_pk_bf16_f32; ds_write_b64 per ni
        float ps = 0.f;
        #pragma unroll
        for (int ni = 0; ni < 4; ++ni) {
            const float p0 = exp2f(s[ni][0] - mrow);
            const float p1 = exp2f(s[ni][1] - mrow);
            const float p2 = exp2f(s[ni][2] - mrow);
            const float p3 = exp2f(s[ni][3] - mrow);
            ps += (p0 + p1) + (p2 + p3);
            uint2 w;
            w.x = pkbf(p0, p1);
            w.y = pkbf(p2, p3);
            const int ch = (2 * ni + (g >> 1)) ^ q7;
            *(uint2*)(sP + (wid * 16 + lr) * 128 + (ch << 4) + ((g & 1) << 3)) = w;
        }
        ps += __shfl_xor(ps, 16);
        ps += __shfl_xor(ps, 32);
        lrow += ps;

        asm volatile("s_waitcnt lgkmcnt(0)" ::: "memory");  // wave-local P visible

        // O^T += V^T P^T
        bf16x8 pf[2];
        #pragma unroll
        for (int ks = 0; ks < 2; ++ks) {
            int ch = (g + 4 * ks) ^ q7;
            pf[ks] = *(const bf16x8*)(sP + (wid * 16 + lr) * 128 + (ch << 4));
        }
        #pragma unroll
        for (int ni = 0; ni < 4; ++ni) {
            #pragma unroll
            for (int ks = 0; ks < 2; ++ks) {
                int row = ni * 16 + lr;            // d row of V^T
                int ch = (g + 4 * ks) ^ q7;
                bf16x8 vf = *(const bf16x8*)(sV[cur] + row * 128 + (ch << 4));
                o[ni] = __builtin_amdgcn_mfma_f32_16x16x32_bf16(vf, pf[ks], o[ni], 0, 0, 0);
            }
        }

        __syncthreads();  // drains prefetch vmcnt + all LDS readers before reuse
    }

    // epilogue: normalize, write O^T into sP as [qrow][d] (swizzled), transpose-read
    const float linv = 1.f / lrow;
    #pragma unroll
    for (int ni = 0; ni < 4; ++ni) {
        uint2 w;
        w.x = pkbf(o[ni][0] * linv, o[ni][1] * linv);
        w.y = pkbf(o[ni][2] * linv, o[ni][3] * linv);
        const int ch = (2 * ni + (g >> 1)) ^ q7;   // d = 16ni+4g+r -> d>>3 = 2ni+(g>>1)
        *(uint2*)(sP + (wid * 16 + lr) * 128 + (ch << 4) + ((g & 1) << 3)) = w;
    }
    __syncthreads();
    #pragma unroll
    for (int i = 0; i < 2; ++i) {
        const int cid = i * 256 + tid;
        const int row = cid >> 3;      // qrow 0..63
        const int ch = cid & 7;        // d-chunk
        uint4 val = *(const uint4*)(sP + row * 128 + ((ch ^ (row & 7)) << 4));
        *(uint4*)&ob[(size_t)(b * TSEQ + q0 + row) * CEMB + h * HDIM + ch * 8] = val;
    }
}

// ---------------------------------------------------------------------------
extern "C" void kernel_launch(void* const* d_in, const int* in_sizes, int n_in,
                              void* d_out, int out_size, void* d_ws, size_t ws_size,
                              hipStream_t stream)
{
    (void)in_sizes; (void)n_in; (void)out_size; (void)ws_size;

    const float* x      = (const float*)d_in[0];
    const float* w_qkv  = (const float*)d_in[1];
    const float* b_qkv  = (const float*)d_in[2];
    const float* w_proj = (const float*)d_in[3];
    const float* b_proj = (const float*)d_in[4];
    float* out = (float*)d_out;

    const int M = BSZ * TSEQ;  // 4096
    unsigned short* xb     = (unsigned short*)d_ws;           // [4096][1024]
    unsigned short* wqkvT  = xb     + (size_t)M * CEMB;       // [3072][1024]
    unsigned short* wprojT = wqkvT  + (size_t)3 * CEMB * CEMB;// [1024][1024]
    unsigned short* qbuf   = wprojT + (size_t)CEMB * CEMB;    // [4096][1024] (pre-scaled)
    unsigned short* kbuf   = qbuf   + (size_t)M * CEMB;       // [4096][1024]
    unsigned short* vbuf   = kbuf   + (size_t)M * CEMB;       // [2][16][64][2048]
    unsigned short* attb   = vbuf   + (size_t)M * CEMB;       // [4096][1024]

    conv_f32_bf16<<<dim3((M * CEMB) / 2048), 256, 0, stream>>>(x, xb);
    conv_transpose_bf16<<<dim3(3 * CEMB / 32, CEMB / 32), 256, 0, stream>>>(
        w_qkv, wqkvT, CEMB, 3 * CEMB);
    conv_transpose_bf16<<<dim3(CEMB / 32, CEMB / 32), 256, 0, stream>>>(
        w_proj, wprojT, CEMB, CEMB);

    gemm_mfma<0><<<dim3(3 * CEMB / 128, M / 128), 256, 0, stream>>>(
        xb, wqkvT, b_qkv, qbuf, kbuf, vbuf, nullptr, M, 3 * CEMB, CEMB);

    flash_mfma<<<dim3(32 * 32), 256, 0, stream>>>(qbuf, kbuf, vbuf, attb);

    gemm_mfma<1><<<dim3(CEMB / 128, M / 128), 256, 0, stream>>>(
        attb, wprojT, b_proj, nullptr, nullptr, nullptr, out, M, CEMB, CEMB);
}

// Round 11
// 187.240 us; speedup vs baseline: 10.7162x; 1.0043x over previous
//
#include <hip/hip_runtime.h>
#include <math.h>

#define BSZ 2
#define TSEQ 2048
#define CEMB 1024
#define NHEAD 16
#define HDIM 64

typedef float f32x4 __attribute__((ext_vector_type(4)));
typedef short bf16x8 __attribute__((ext_vector_type(8)));

typedef __attribute__((address_space(3))) char lds_char;
typedef __attribute__((address_space(1))) const char gbl_char;

__device__ __forceinline__ void g2l16(const void* g, void* l) {
    // async global->LDS, 16B per lane; LDS dest = wave-uniform base + lane*16
    __builtin_amdgcn_global_load_lds((const gbl_char*)g, (lds_char*)l, 16, 0, 0);
}

__device__ __forceinline__ unsigned short f2bf(float x) {
    unsigned u = __float_as_uint(x);
    unsigned r = ((u >> 16) & 1u) + 0x7fffu;   // round-to-nearest-even
    return (unsigned short)((u + r) >> 16);
}

__device__ __forceinline__ unsigned pkbf(float lo, float hi) {
    // 2x f32 -> packed 2x bf16 in one VALU op (guide T12 recipe; no builtin)
    unsigned r;
    asm("v_cvt_pk_bf16_f32 %0, %1, %2" : "=v"(r) : "v"(lo), "v"(hi));
    return r;
}

// ---------------------------------------------------------------------------
// fp32 -> bf16 elementwise (8 elems/thread, 16B stores)
// ---------------------------------------------------------------------------
__global__ __launch_bounds__(256) void conv_f32_bf16(
    const float* __restrict__ in, unsigned short* __restrict__ out)
{
    size_t i = ((size_t)blockIdx.x * 256 + threadIdx.x) * 8;
    float4 a = *(const float4*)(in + i);
    float4 b = *(const float4*)(in + i + 4);
    union { unsigned short u[8]; uint4 v; } pk;
    pk.u[0] = f2bf(a.x); pk.u[1] = f2bf(a.y); pk.u[2] = f2bf(a.z); pk.u[3] = f2bf(a.w);
    pk.u[4] = f2bf(b.x); pk.u[5] = f2bf(b.y); pk.u[6] = f2bf(b.z); pk.u[7] = f2bf(b.w);
    *(uint4*)(out + i) = pk.v;
}

// ---------------------------------------------------------------------------
// fp32 [K][N] -> bf16 transposed [N][K]
// ---------------------------------------------------------------------------
__global__ __launch_bounds__(256) void conv_transpose_bf16(
    const float* __restrict__ w, unsigned short* __restrict__ wT, int K, int N)
{
    __shared__ float t[32][33];
    const int n0 = blockIdx.x * 32, k0 = blockIdx.y * 32;
    const int tx = threadIdx.x & 31, ty = threadIdx.x >> 5;  // 32 x 8
    #pragma unroll
    for (int i = 0; i < 4; ++i)
        t[ty + i * 8][tx] = w[(size_t)(k0 + ty + i * 8) * N + n0 + tx];
    __syncthreads();
    #pragma unroll
    for (int i = 0; i < 4; ++i) {
        int r = ty + i * 8;
        wT[(size_t)(n0 + r) * K + k0 + tx] = f2bf(t[tx][r]);
    }
}

// ---------------------------------------------------------------------------
// bf16 MFMA GEMM: C[M,N] = A[M,K] @ BT[N,K]^T + bias
// EPI=0: QKV epilogue (Q pre-scaled by log2e/32, K bf16, V transposed).
// EPI=1: fp32 out + bias.
// ---------------------------------------------------------------------------
template <int EPI>
__global__ __launch_bounds__(256) void gemm_mfma(
    const unsigned short* __restrict__ A, const unsigned short* __restrict__ BT,
    const float* __restrict__ bias,
    unsigned short* __restrict__ qo, unsigned short* __restrict__ ko,
    unsigned short* __restrict__ vo, float* __restrict__ fo,
    int M, int N, int K)
{
    __shared__ __align__(16) char sA[128 * 64 * 2];
    __shared__ __align__(16) char sB[128 * 64 * 2];

    const int tid = threadIdx.x;
    const int lane = tid & 63;
    const int wid = tid >> 6;
    const int wm = wid >> 1, wn = wid & 1;
    const int row0 = blockIdx.y * 128;
    const int col0 = blockIdx.x * 128;

    f32x4 acc[4][4] = {};

    for (int k0 = 0; k0 < K; k0 += 64) {
        __syncthreads();
        #pragma unroll
        for (int i = 0; i < 4; ++i) {
            int cid = i * 256 + tid;
            int row = cid >> 3, c2 = cid & 7;
            g2l16(&A[(size_t)(row0 + row) * K + k0 + ((c2 ^ (row & 7)) << 3)],
                  sA + ((i * 256 + (tid & 192)) << 4));
        }
        #pragma unroll
        for (int i = 0; i < 4; ++i) {
            int cid = i * 256 + tid;
            int row = cid >> 3, c2 = cid & 7;
            g2l16(&BT[(size_t)(col0 + row) * K + k0 + ((c2 ^ (row & 7)) << 3)],
                  sB + ((i * 256 + (tid & 192)) << 4));
        }
        __syncthreads();

        #pragma unroll
        for (int ks = 0; ks < 2; ++ks) {
            bf16x8 af[4], bf[4];
            #pragma unroll
            for (int mi = 0; mi < 4; ++mi) {
                int row = wm * 64 + mi * 16 + (lane & 15);
                int ch = ((lane >> 4) + 4 * ks) ^ (row & 7);
                af[mi] = *(const bf16x8*)(sA + row * 128 + (ch << 4));
            }
            #pragma unroll
            for (int ni = 0; ni < 4; ++ni) {
                int row = wn * 64 + ni * 16 + (lane & 15);
                int ch = ((lane >> 4) + 4 * ks) ^ (row & 7);
                bf[ni] = *(const bf16x8*)(sB + row * 128 + (ch << 4));
            }
            #pragma unroll
            for (int mi = 0; mi < 4; ++mi)
                #pragma unroll
                for (int ni = 0; ni < 4; ++ni)
                    acc[mi][ni] = __builtin_amdgcn_mfma_f32_16x16x32_bf16(
                        af[mi], bf[ni], acc[mi][ni], 0, 0, 0);
        }
    }

    #pragma unroll
    for (int mi = 0; mi < 4; ++mi) {
        const int rg = row0 + wm * 64 + mi * 16 + (lane >> 4) * 4;
        #pragma unroll
        for (int ni = 0; ni < 4; ++ni) {
            const int cg = col0 + wn * 64 + ni * 16 + (lane & 15);
            const float bv = bias[cg];
            if (EPI == 1) {
                #pragma unroll
                for (int r = 0; r < 4; ++r)
                    fo[(size_t)(rg + r) * N + cg] = acc[mi][ni][r] + bv;
            } else {
                const int region = col0 >> 10;
                if (region < 2) {
                    unsigned short* dst = region ? ko : qo;
                    // fold softmax scale (in exp2 domain) into Q at the source
                    const float sc = region ? 1.f : 0.0450744431f;  // log2(e)/32
                    const int nn = cg - (region << 10);
                    #pragma unroll
                    for (int r = 0; r < 4; ++r)
                        dst[(size_t)(rg + r) * CEMB + nn] = f2bf((acc[mi][ni][r] + bv) * sc);
                } else {
                    const int nloc = cg - 2048;
                    const int h = nloc >> 6, d = nloc & 63;
                    const int b = rg >> 11, t = rg & 2047;
                    ushort4 pk;
                    pk.x = f2bf(acc[mi][ni][0] + bv);
                    pk.y = f2bf(acc[mi][ni][1] + bv);
                    pk.z = f2bf(acc[mi][ni][2] + bv);
                    pk.w = f2bf(acc[mi][ni][3] + bv);
                    *(ushort4*)&vo[(((size_t)b * NHEAD + h) * HDIM + d) * TSEQ + t] = pk;
                }
            }
        }
    }
}

// ---------------------------------------------------------------------------
// MFMA flash attention, swapped QK^T, double-buffered K/V, 1 barrier/tile.
// Block map (XCD- and CU-aware):
//   bh = bid & 31  -> all 32 q-tiles of one head land on ONE XCD (bid%8 = bh%8),
//                     each XCD serves 4 heads = 2 MB K/V, fits its 4 MB L2.
//   j  = bid >> 5; qt_raw = ((j&7)<<2)|(j>>3); qt = interleave(qt_raw)
//                  -> per-CU (stride-256 dispatch) qt set {2j0,2j0+1,30-2j0,31-2j0},
//                     work sum == 66 exactly on every CU.
// Q pre-scaled by log2e/32 at the QKV GEMM -> S already in exp2 domain.
// ---------------------------------------------------------------------------
__global__ __launch_bounds__(256) void flash_mfma(
    const unsigned short* __restrict__ qb, const unsigned short* __restrict__ kb,
    const unsigned short* __restrict__ vt, unsigned short* __restrict__ ob)
{
    const int bid = blockIdx.x;
    const int bh = bid & 31;
    const int j = bid >> 5;
    const int qt_raw = ((j & 7) << 2) | (j >> 3);
    const int qt = (qt_raw & 1) ? (31 - (qt_raw >> 1)) : (qt_raw >> 1);
    const int b = bh >> 4, h = bh & 15;
    const int q0 = qt * 64;

    __shared__ __align__(16) char sK[2][8192];
    __shared__ __align__(16) char sV[2][8192];
    __shared__ __align__(16) char sP[8192];

    const int tid = threadIdx.x;
    const int lane = tid & 63;
    const int wid = tid >> 6;
    const int g = lane >> 4;       // lane group 0..3
    const int lr = lane & 15;      // this lane's q-row within the wave stripe
    const int q7 = lr & 7;

    // stage Q (via sP) + K/V tile 0 (buf 0)
    #pragma unroll
    for (int i = 0; i < 2; ++i) {
        int cid = i * 256 + tid;
        int row = cid >> 3, c2 = cid & 7;
        g2l16(&qb[(size_t)(b * TSEQ + q0 + row) * CEMB + h * HDIM + ((c2 ^ (row & 7)) << 3)],
              sP + ((i * 256 + (tid & 192)) << 4));
        g2l16(&kb[(size_t)(b * TSEQ + row) * CEMB + h * HDIM + ((c2 ^ (row & 7)) << 3)],
              sK[0] + ((i * 256 + (tid & 192)) << 4));
        g2l16(&vt[(((size_t)b * NHEAD + h) * HDIM + row) * TSEQ + ((c2 ^ (row & 7)) << 3)],
              sV[0] + ((i * 256 + (tid & 192)) << 4));
    }
    __syncthreads();   // drain all staging

    // Q fragments: loop-invariant, held in registers
    bf16x8 qf[2];
    #pragma unroll
    for (int ks = 0; ks < 2; ++ks) {
        int ch = (g + 4 * ks) ^ q7;
        qf[ks] = *(const bf16x8*)(sP + (wid * 16 + lr) * 128 + (ch << 4));
    }
    __syncthreads();   // all waves have Q before sP becomes the P buffer

    f32x4 o[4] = {};                 // O^T: o[ni][r] = O[d=16ni+4g+r][qrow]
    float mrow = -INFINITY, lrow = 0.f;
    const int qrow_g = q0 + wid * 16 + lr;

    for (int kt = 0; kt <= qt; ++kt) {
        const int cur = kt & 1;

        // prefetch next K/V while this tile computes (drained at end-of-tile sync)
        if (kt < qt) {
            const int k0n = (kt + 1) * 64;
            const int nxt = cur ^ 1;
            #pragma unroll
            for (int i = 0; i < 2; ++i) {
                int cid = i * 256 + tid;
                int row = cid >> 3, c2 = cid & 7;
                g2l16(&kb[(size_t)(b * TSEQ + k0n + row) * CEMB + h * HDIM + ((c2 ^ (row & 7)) << 3)],
                      sK[nxt] + ((i * 256 + (tid & 192)) << 4));
                g2l16(&vt[(((size_t)b * NHEAD + h) * HDIM + row) * TSEQ + k0n + ((c2 ^ (row & 7)) << 3)],
                      sV[nxt] + ((i * 256 + (tid & 192)) << 4));
            }
        }

        // S^T = K Q^T : s[ni][r] = S[key=16ni+4g+r][qrow=lr] (exp2 domain)
        f32x4 s[4] = {};
        #pragma unroll
        for (int ni = 0; ni < 4; ++ni) {
            #pragma unroll
            for (int ks = 0; ks < 2; ++ks) {
                int row = ni * 16 + lr;
                int ch = (g + 4 * ks) ^ q7;
                bf16x8 kf = *(const bf16x8*)(sK[cur] + row * 128 + (ch << 4));
                s[ni] = __builtin_amdgcn_mfma_f32_16x16x32_bf16(kf, qf[ks], s[ni], 0, 0, 0);
            }
        }

        // causal mask (diagonal tile only)
        if (kt == qt) {
            const int k0 = kt * 64;
            #pragma unroll
            for (int ni = 0; ni < 4; ++ni)
                #pragma unroll
                for (int r = 0; r < 4; ++r)
                    if (k0 + ni * 16 + g * 4 + r > qrow_g) s[ni][r] = -INFINITY;
        }

        // row max: linear fmax chain (fuses to v_max3) + 2 shfl
        float v = s[0][0];
        v = fmaxf(v, s[0][1]); v = fmaxf(v, s[0][2]); v = fmaxf(v, s[0][3]);
        v = fmaxf(v, s[1][0]); v = fmaxf(v, s[1][1]); v = fmaxf(v, s[1][2]); v = fmaxf(v, s[1][3]);
        v = fmaxf(v, s[2][0]); v = fmaxf(v, s[2][1]); v = fmaxf(v, s[2][2]); v = fmaxf(v, s[2][3]);
        v = fmaxf(v, s[3][0]); v = fmaxf(v, s[3][1]); v = fmaxf(v, s[3][2]); v = fmaxf(v, s[3][3]);
        v = fmaxf(v, __shfl_xor(v, 16));
        v = fmaxf(v, __shfl_xor(v, 32));

        // defer-max: rescale only when max grew by > 8 (P <= 2^8)
        if (!__all(v <= mrow + 8.f)) {
            const float mnew = fmaxf(mrow, v);
            const float sc = exp2f(mrow - mnew);   // first tile: exp2(-inf)=0
            lrow *= sc;
            #pragma unroll
            for (int ni = 0; ni < 4; ++ni)
                #pragma unroll
                for (int r = 0; r < 4; ++r)
                    o[ni][r] *= sc;
            mrow = mnew;
        }

        // P = exp2(S - m); pack via v_cvt_pk_bf16_f32; ds_write_b64 per ni
        float ps = 0.f;
        #pragma unroll
        for (int ni = 0; ni < 4; ++ni) {
            const float p0 = exp2f(s[ni][0] - mrow);
            const float p1 = exp2f(s[ni][1] - mrow);
            const float p2 = exp2f(s[ni][2] - mrow);
            const float p3 = exp2f(s[ni][3] - mrow);
            ps += (p0 + p1) + (p2 + p3);
            uint2 w;
            w.x = pkbf(p0, p1);
            w.y = pkbf(p2, p3);
            const int ch = (2 * ni + (g >> 1)) ^ q7;
            *(uint2*)(sP + (wid * 16 + lr) * 128 + (ch << 4) + ((g & 1) << 3)) = w;
        }
        ps += __shfl_xor(ps, 16);
        ps += __shfl_xor(ps, 32);
        lrow += ps;

        asm volatile("s_waitcnt lgkmcnt(0)" ::: "memory");  // wave-local P visible

        // O^T += V^T P^T
        bf16x8 pf[2];
        #pragma unroll
        for (int ks = 0; ks < 2; ++ks) {
            int ch = (g + 4 * ks) ^ q7;
            pf[ks] = *(const bf16x8*)(sP + (wid * 16 + lr) * 128 + (ch << 4));
        }
        #pragma unroll
        for (int ni = 0; ni < 4; ++ni) {
            #pragma unroll
            for (int ks = 0; ks < 2; ++ks) {
                int row = ni * 16 + lr;            // d row of V^T
                int ch = (g + 4 * ks) ^ q7;
                bf16x8 vf = *(const bf16x8*)(sV[cur] + row * 128 + (ch << 4));
                o[ni] = __builtin_amdgcn_mfma_f32_16x16x32_bf16(vf, pf[ks], o[ni], 0, 0, 0);
            }
        }

        __syncthreads();  // drains prefetch vmcnt + all LDS readers before reuse
    }

    // epilogue: normalize, write O^T into sP as [qrow][d] (swizzled), transpose-read
    const float linv = 1.f / lrow;
    #pragma unroll
    for (int ni = 0; ni < 4; ++ni) {
        uint2 w;
        w.x = pkbf(o[ni][0] * linv, o[ni][1] * linv);
        w.y = pkbf(o[ni][2] * linv, o[ni][3] * linv);
        const int ch = (2 * ni + (g >> 1)) ^ q7;   // d = 16ni+4g+r -> d>>3 = 2ni+(g>>1)
        *(uint2*)(sP + (wid * 16 + lr) * 128 + (ch << 4) + ((g & 1) << 3)) = w;
    }
    __syncthreads();
    #pragma unroll
    for (int i = 0; i < 2; ++i) {
        const int cid = i * 256 + tid;
        const int row = cid >> 3;      // qrow 0..63
        const int ch = cid & 7;        // d-chunk
        uint4 val = *(const uint4*)(sP + row * 128 + ((ch ^ (row & 7)) << 4));
        *(uint4*)&ob[(size_t)(b * TSEQ + q0 + row) * CEMB + h * HDIM + ch * 8] = val;
    }
}

// ---------------------------------------------------------------------------
extern "C" void kernel_launch(void* const* d_in, const int* in_sizes, int n_in,
                              void* d_out, int out_size, void* d_ws, size_t ws_size,
                              hipStream_t stream)
{
    (void)in_sizes; (void)n_in; (void)out_size; (void)ws_size;

    const float* x      = (const float*)d_in[0];
    const float* w_qkv  = (const float*)d_in[1];
    const float* b_qkv  = (const float*)d_in[2];
    const float* w_proj = (const float*)d_in[3];
    const float* b_proj = (const float*)d_in[4];
    float* out = (float*)d_out;

    const int M = BSZ * TSEQ;  // 4096
    unsigned short* xb     = (unsigned short*)d_ws;           // [4096][1024]
    unsigned short* wqkvT  = xb     + (size_t)M * CEMB;       // [3072][1024]
    unsigned short* wprojT = wqkvT  + (size_t)3 * CEMB * CEMB;// [1024][1024]
    unsigned short* qbuf   = wprojT + (size_t)CEMB * CEMB;    // [4096][1024] (pre-scaled)
    unsigned short* kbuf   = qbuf   + (size_t)M * CEMB;       // [4096][1024]
    unsigned short* vbuf   = kbuf   + (size_t)M * CEMB;       // [2][16][64][2048]
    unsigned short* attb   = vbuf   + (size_t)M * CEMB;       // [4096][1024]

    conv_f32_bf16<<<dim3((M * CEMB) / 2048), 256, 0, stream>>>(x, xb);
    conv_transpose_bf16<<<dim3(3 * CEMB / 32, CEMB / 32), 256, 0, stream>>>(
        w_qkv, wqkvT, CEMB, 3 * CEMB);
    conv_transpose_bf16<<<dim3(CEMB / 32, CEMB / 32), 256, 0, stream>>>(
        w_proj, wprojT, CEMB, CEMB);

    gemm_mfma<0><<<dim3(3 * CEMB / 128, M / 128), 256, 0, stream>>>(
        xb, wqkvT, b_qkv, qbuf, kbuf, vbuf, nullptr, M, 3 * CEMB, CEMB);

    flash_mfma<<<dim3(32 * 32), 256, 0, stream>>>(qbuf, kbuf, vbuf, attb);

    gemm_mfma<1><<<dim3(CEMB / 128, M / 128), 256, 0, stream>>>(
        attb, wprojT, b_proj, nullptr, nullptr, nullptr, out, M, CEMB, CEMB);
}